// Round 13
// baseline (177.922 us; speedup 1.0000x reference)
//
#include <hip/hip_runtime.h>

// Causal linear attention (chunked scan), bf16 MFMA end-to-end.
// q = softmax(x Wq^T), k = softmax(x Wk^T), v = x Wv^T   (one fused MFMA GEMM)
// chunk_T : T_c = sum_t v_t^T (x) k_t per (n,h,c)  (MFMA, fp32 out, 16KB/tile)
// attn4   : Tpre = sum_{c'<c} T_c' in 16 regs (L2-resident ct, chunk order =
//           identical fp32 association as a serial scan); Ts = bf16(Tpre);
//           out = Q Ts^T + tril(Q K^T) V.
// R13: tail de-materialized -- R12 showed total-gemm ~113us invariant across
// four tail structures; this removes the cs/segtot round-trip (the part of
// that 113 I can address) while keeping all kernel shapes <=512 thr (the
// 1024-thr/144KB shapes measurably depressed co-scheduled gemm 2/2 times).

constexpr int DIM  = 1024;
constexpr int H    = 16;
constexpr int DH   = 64;
constexpr int LSEQ = 2048;
constexpr int NB   = 2;
constexpr int MTOK = NB * LSEQ;   // 4096 tokens
constexpr int CS   = 64;          // chunk size
constexpr int NC   = LSEQ / CS;   // 32 chunks

typedef __bf16 bf16x8 __attribute__((ext_vector_type(8)));
typedef float floatx4 __attribute__((ext_vector_type(4)));
typedef unsigned short ushort_t;

__device__ __forceinline__ ushort_t f2bf(float f) {
  unsigned int u = __float_as_uint(f);
  u += 0x7FFFu + ((u >> 16) & 1u);   // RTNE
  return (ushort_t)(u >> 16);
}

__device__ __forceinline__ void async16(void* lds, const void* g) {
  __builtin_amdgcn_global_load_lds(
      (const __attribute__((address_space(1))) unsigned int*)g,
      (__attribute__((address_space(3))) unsigned int*)lds, 16, 0, 0);
}

// read a bf16x8 fragment from a transposed stride-33-uint LDS array
__device__ __forceinline__ bf16x8 tfrag(const unsigned int* T, int row, int uoff) {
  union { bf16x8 v; unsigned int u[4]; } r;
  const unsigned int* p = T + row * 33 + uoff;
  r.u[0] = p[0]; r.u[1] = p[1]; r.u[2] = p[2]; r.u[3] = p[3];
  return r.v;
}

// transpose a 64x64 bf16 tile (global, row stride DIM) into stride-33-uint LDS
// (tid must be 0..255)
__device__ __forceinline__ void transpose_tile(const ushort_t* g, unsigned int* TT, int tid) {
  const int ic = tid & 7, tp = tid >> 3;       // tp 0..31, ic 0..7
  const ushort_t* r0 = g + (size_t)(2 * tp) * DIM + ic * 8;
  union { uint4 q; ushort_t u[8]; } a0, a1;
  a0.q = *(const uint4*)r0;
  a1.q = *(const uint4*)(r0 + DIM);
#pragma unroll
  for (int j = 0; j < 8; j++)
    TT[(8 * ic + j) * 33 + tp] = (unsigned int)a0.u[j] | ((unsigned int)a1.u[j] << 16);
}

// ------------- cast fp32 -> bf16 for query/key and the three weights --------
__global__ __launch_bounds__(256) void cast_all(const float* __restrict__ q,
                                                const float* __restrict__ k,
                                                const float* __restrict__ wq,
                                                const float* __restrict__ wk,
                                                const float* __restrict__ wv,
                                                ushort_t* __restrict__ xbf,
                                                ushort_t* __restrict__ wbf) {
  const int seg = blockIdx.y;
  const float* src;
  ushort_t* dst;
  int n4;
  if (seg == 0)      { src = q;  dst = xbf;                  n4 = (4 << 20) / 4; }
  else if (seg == 1) { src = k;  dst = xbf + (4 << 20);      n4 = (4 << 20) / 4; }
  else if (seg == 2) { src = wq; dst = wbf;                  n4 = (1 << 20) / 4; }
  else if (seg == 3) { src = wk; dst = wbf + (1 << 20);      n4 = (1 << 20) / 4; }
  else               { src = wv; dst = wbf + (2 << 20);      n4 = (1 << 20) / 4; }
  for (int i = blockIdx.x * 256 + threadIdx.x; i < n4; i += gridDim.x * 256) {
    const float4 f = ((const float4*)src)[i];
    ((ushort4*)dst)[i] = make_ushort4(f2bf(f.x), f2bf(f.y), f2bf(f.z), f2bf(f.w));
  }
}

// ----- fused bf16 MFMA GEMM NT: z in {0:q,1:k,2:v}, tile 256x256, BK=64 -----
// R6 schedule (best measured, 46.5us): 8 waves (2M x 4N), 16 K-tiles of BK=64,
// 4 phases/K-tile, counted vmcnt(4) once per K-tile, setprio around MFMA,
// LDS XOR-swizzle chunk^=(row&7) source+read (0 bank conflicts measured).
__global__ __launch_bounds__(512, 2) void gemm_fused(const ushort_t* __restrict__ xbf,
                                                     const ushort_t* __restrict__ wbf,
                                                     ushort_t* __restrict__ qp,
                                                     ushort_t* __restrict__ kp,
                                                     ushort_t* __restrict__ vp) {
  __shared__ __align__(16) ushort_t sh[65536];   // 128 KB
  const int tid = threadIdx.x;

  // XCD-aware decode: 192 blocks = 8 XCDs x 24 (HW round-robins blockIdx%8).
  const int xcd   = blockIdx.x & 7;
  const int local = blockIdx.x >> 3;            // 0..23
  const int T     = xcd * 24 + local;           // 0..191
  const int z     = T >> 6;                     // 0..2
  const int rem   = T & 63;
  const int bm    = (rem >> 2) * 256;
  const int bn    = (rem & 3) * 256;

  const ushort_t* A = xbf + (z ? (size_t)(4 << 20) : 0);
  const ushort_t* W = wbf + (size_t)z * (1 << 20);
  ushort_t* C = (z == 0) ? qp : ((z == 1) ? kp : vp);

  const int lane  = tid & 63;
  const int wid   = tid >> 6;
  const int wr    = wid >> 2, wc = wid & 3;     // wave grid 2(M) x 4(N)
  const int row16 = lane & 15, quad = lane >> 4;

  floatx4 acc[8][4] = {};

  const int srow = tid >> 3;                        // 0..63
  const int lc   = (tid & 7) ^ (srow & 7);
  const ushort_t* pA[2][2];
  const ushort_t* pB[2][2];
#pragma unroll
  for (int h = 0; h < 2; h++)
#pragma unroll
    for (int rnd = 0; rnd < 2; rnd++) {
      pA[h][rnd] = A + (size_t)(bm + h * 128 + rnd * 64 + srow) * DIM + lc * 8;
      pB[h][rnd] = W + (size_t)(bn + h * 128 + rnd * 64 + srow) * DIM + lc * 8;
    }
  char* shW = (char*)sh;

#define STG(b, ism, h, kt)                                          \
  {                                                                 \
    char* d_ = shW + (b) * 65536 + (ism) * 32768 + (h) * 16384 + tid * 16; \
    async16(d_,        ((ism) ? pB : pA)[h][0] + (size_t)(kt) * 64);       \
    async16(d_ + 8192, ((ism) ? pB : pA)[h][1] + (size_t)(kt) * 64);       \
  }

  const int key = row16 & 7;
  const int xc0 = (quad ^ key) * 16;          // kk=0 chunk byte
  const int xc1 = ((4 + quad) ^ key) * 16;    // kk=1 chunk byte
  const int aOff = wr * 16384 + row16 * 128;  // + p*65536 + mt*2048
  const int bOff = 32768 + (wc >> 1) * 16384 + (wc & 1) * 8192 + row16 * 128;
  const char* shR = (const char*)sh;

  bf16x8 aF[4][2], bF[4][2];

#define RD_A4(p, base)                                                        \
  {                                                                           \
    _Pragma("unroll")                                                         \
    for (int mt = 0; mt < 4; mt++) {                                          \
      aF[mt][0] = *(const bf16x8*)(shR + (p) * 65536 + aOff + ((base) + mt) * 2048 + xc0); \
      aF[mt][1] = *(const bf16x8*)(shR + (p) * 65536 + aOff + ((base) + mt) * 2048 + xc1); \
    }                                                                         \
  }
#define RD_B2(p, base)                                                        \
  {                                                                           \
    _Pragma("unroll")                                                         \
    for (int j = 0; j < 2; j++) {                                             \
      bF[(base) + j][0] = *(const bf16x8*)(shR + (p) * 65536 + bOff + ((base) + j) * 2048 + xc0); \
      bF[(base) + j][1] = *(const bf16x8*)(shR + (p) * 65536 + bOff + ((base) + j) * 2048 + xc1); \
    }                                                                         \
  }
#define MFMA8(mb, nb)                                                         \
  {                                                                           \
    _Pragma("unroll")                                                         \
    for (int mt = 0; mt < 4; mt++)                                            \
      _Pragma("unroll")                                                       \
      for (int nt = 0; nt < 2; nt++) {                                        \
        acc[(mb) + mt][(nb) + nt] = __builtin_amdgcn_mfma_f32_16x16x32_bf16(  \
            aF[mt][0], bF[(nb) + nt][0], acc[(mb) + mt][(nb) + nt], 0, 0, 0); \
        acc[(mb) + mt][(nb) + nt] = __builtin_amdgcn_mfma_f32_16x16x32_bf16(  \
            aF[mt][1], bF[(nb) + nt][1], acc[(mb) + mt][(nb) + nt], 0, 0, 0); \
      }                                                                       \
  }
#define BARD()  asm volatile("s_barrier" ::: "memory")
#define LGKM0() asm volatile("s_waitcnt lgkmcnt(0)" ::: "memory")

  STG(0, 0, 0, 0); STG(0, 1, 0, 0);   // 0.A0, 0.B0
  STG(0, 1, 1, 0); STG(0, 0, 1, 0);   // 0.B1, 0.A1
  STG(1, 0, 0, 1); STG(1, 1, 0, 1);   // 1.A0, 1.B0
  asm volatile("s_waitcnt vmcnt(4)" ::: "memory");
  BARD();

  for (int u = 0; u < 16; ++u) {
    const int p  = u & 1;
    const int qb = p ^ 1;
    RD_A4(p, 0); RD_B2(p, 0);
    if (u + 1 < 16) { STG(qb, 1, 1, u + 1); STG(qb, 0, 1, u + 1); }
    BARD(); LGKM0();
    __builtin_amdgcn_s_setprio(1); MFMA8(0, 0); __builtin_amdgcn_s_setprio(0);
    BARD();
    RD_B2(p, 2);
    BARD(); LGKM0();
    __builtin_amdgcn_s_setprio(1); MFMA8(0, 2); __builtin_amdgcn_s_setprio(0);
    BARD();
    RD_A4(p, 4);
    BARD(); LGKM0();
    __builtin_amdgcn_s_setprio(1); MFMA8(4, 0); __builtin_amdgcn_s_setprio(0);
    BARD();
    if (u + 2 < 16) {
      STG(p, 0, 0, u + 2); STG(p, 1, 0, u + 2);
      asm volatile("s_waitcnt vmcnt(4)" ::: "memory");
    } else {
      asm volatile("s_waitcnt vmcnt(0)" ::: "memory");
    }
    BARD();
    __builtin_amdgcn_s_setprio(1); MFMA8(4, 2); __builtin_amdgcn_s_setprio(0);
    BARD();
  }
#undef STG
#undef RD_A4
#undef RD_B2
#undef MFMA8
#undef BARD
#undef LGKM0
  __syncthreads();   // all LDS traffic done before reuse as repack buffer

  if (z < 2) {
    // in-register per-head softmax: row (mt,quad,r) spans nt regs x 16 lanes
#pragma unroll
    for (int mt = 0; mt < 8; mt++)
#pragma unroll
      for (int r = 0; r < 4; r++) {
        float m = fmaxf(fmaxf(acc[mt][0][r], acc[mt][1][r]),
                        fmaxf(acc[mt][2][r], acc[mt][3][r]));
#pragma unroll
        for (int o = 1; o < 16; o <<= 1) m = fmaxf(m, __shfl_xor(m, o, 64));
        float e[4], s = 0.f;
#pragma unroll
        for (int nt = 0; nt < 4; nt++) { e[nt] = __expf(acc[mt][nt][r] - m); s += e[nt]; }
#pragma unroll
        for (int o = 1; o < 16; o <<= 1) s += __shfl_xor(s, o, 64);
        const float inv = 1.f / s;
#pragma unroll
        for (int nt = 0; nt < 4; nt++) acc[mt][nt][r] = e[nt] * inv;
      }
  }

  // epilogue: 4 rounds of 64 rows; repack via LDS (stride 264), 16B stores
  ushort_t* CsB = sh;
#pragma unroll
  for (int p4 = 0; p4 < 4; ++p4) {
    __syncthreads();
    if (wr == (p4 >> 1)) {
      const int mh = (p4 & 1) * 4;
#pragma unroll
      for (int m4 = 0; m4 < 4; m4++)
#pragma unroll
        for (int nt = 0; nt < 4; nt++)
#pragma unroll
          for (int r = 0; r < 4; r++)
            CsB[(m4 * 16 + quad * 4 + r) * 264 + wc * 64 + nt * 16 + row16] =
                f2bf(acc[mh + m4][nt][r]);
    }
    __syncthreads();
#pragma unroll
    for (int it = 0; it < 4; it++) {
      const int ch = tid + it * 512;        // 0..2047 = 64 rows x 32 chunks
      const int row = ch >> 5, ic = ch & 31;
      *(uint4*)&C[(size_t)(bm + p4 * 64 + row) * DIM + bn + ic * 8] =
          *(const uint4*)&CsB[row * 264 + ic * 8];
    }
  }
}

// ------- chunk_T: T_c[j][i] = sum_t V[t][j] K[t][i]  (MFMA, fp32 out) -------
// grid (NC, H, NB) = 1024 blocks, 256 thr. Writes ONLY per-chunk totals ct.
__global__ __launch_bounds__(256) void chunk_T(const ushort_t* __restrict__ kp,
                                               const ushort_t* __restrict__ vp,
                                               float* __restrict__ ct) {
  __shared__ unsigned int KT[64 * 33];
  __shared__ unsigned int VT[64 * 33];
  const int c = blockIdx.x, h = blockIdx.y, n = blockIdx.z;
  const int tid = threadIdx.x;
  const size_t gbase = ((size_t)(n * LSEQ + c * CS)) * DIM + h * DH;

  transpose_tile(kp + gbase, KT, tid);
  transpose_tile(vp + gbase, VT, tid);
  __syncthreads();

  const int lane = tid & 63, wid = tid >> 6;
  const int row16 = lane & 15, quad = lane >> 4;

  floatx4 acc[4] = {};
#pragma unroll
  for (int ks = 0; ks < 2; ks++) {
    const bf16x8 a = tfrag(VT, wid * 16 + row16, ks * 16 + quad * 4);
#pragma unroll
    for (int nt = 0; nt < 4; nt++) {
      const bf16x8 b = tfrag(KT, nt * 16 + row16, ks * 16 + quad * 4);
      acc[nt] = __builtin_amdgcn_mfma_f32_16x16x32_bf16(a, b, acc[nt], 0, 0, 0);
    }
  }
  float* outp = ct + ((size_t)((n * H + h) * NC + c)) * (DH * DH);
#pragma unroll
  for (int nt = 0; nt < 4; nt++)
#pragma unroll
    for (int r = 0; r < 4; r++)
      outp[(wid * 16 + quad * 4 + r) * DH + nt * 16 + row16] = acc[nt][r];
}

// ---- attn4: one chunk per block; Tpre in regs from L2-resident ct ----------
// Tpre = sum_{c'<c} T_c' accumulated in chunk order (identical fp32
// association as a serial exclusive scan). Ts = bf16(Tpre).
// out = Q Ts^T + tril(Q K^T) V.  grid (NC, H, NB) = 1024 blocks, 45.3 KB LDS.
__global__ __launch_bounds__(256) void attn4(const ushort_t* __restrict__ qp,
                                             const ushort_t* __restrict__ kp,
                                             const ushort_t* __restrict__ vp,
                                             const float* __restrict__ ct,
                                             float* __restrict__ out) {
  __shared__ ushort_t Qs[64 * 72];
  __shared__ ushort_t Ks[64 * 72];
  __shared__ ushort_t Ts[64 * 72];
  __shared__ ushort_t Pb[64 * 72];
  __shared__ unsigned int VT[64 * 33];
  const int c = blockIdx.x, h = blockIdx.y, n = blockIdx.z;
  const int tid = threadIdx.x;
  const int lane = tid & 63, wid = tid >> 6;
  const int row16 = lane & 15, quad = lane >> 4;
  const int nh = n * H + h;
  const size_t gbase = ((size_t)(n * LSEQ + c * CS)) * DIM + h * DH;

  // Tpre at this thread's 16 Ts elements (e = (tid+ii*256)*8 .. +7)
  float sb[16] = {0.f, 0.f, 0.f, 0.f, 0.f, 0.f, 0.f, 0.f,
                  0.f, 0.f, 0.f, 0.f, 0.f, 0.f, 0.f, 0.f};
  {
    const float* base = ct + (size_t)nh * NC * (DH * DH);
    for (int cp = 0; cp < c; cp++) {
      const float* bsp = base + (size_t)cp * (DH * DH);
#pragma unroll
      for (int ii = 0; ii < 2; ii++) {
        const int e = (tid + ii * 256) * 8;
        const float4 u0 = *(const float4*)(bsp + e);
        const float4 u1 = *(const float4*)(bsp + e + 4);
        sb[ii * 8 + 0] += u0.x; sb[ii * 8 + 1] += u0.y;
        sb[ii * 8 + 2] += u0.z; sb[ii * 8 + 3] += u0.w;
        sb[ii * 8 + 4] += u1.x; sb[ii * 8 + 5] += u1.y;
        sb[ii * 8 + 6] += u1.z; sb[ii * 8 + 7] += u1.w;
      }
    }
  }

  // stage Q,K (bf16), V transposed, Ts = bf16(Tpre)
#pragma unroll
  for (int it = 0; it < 2; it++) {
    const int ch = tid + it * 256;           // 0..511
    const int row = ch >> 3, ic = ch & 7;
    *(uint4*)&Qs[row * 72 + ic * 8] = *(const uint4*)&qp[gbase + (size_t)row * DIM + ic * 8];
    *(uint4*)&Ks[row * 72 + ic * 8] = *(const uint4*)&kp[gbase + (size_t)row * DIM + ic * 8];
  }
  transpose_tile(vp + gbase, VT, tid);
#pragma unroll
  for (int ii = 0; ii < 2; ii++) {
    const int e = (tid + ii * 256) * 8;      // 0..4088, step 8
    const int row = e >> 6, col = e & 63;
    ushort_t* d = &Ts[row * 72 + col];
    *(ushort4*)d = make_ushort4(f2bf(sb[ii * 8 + 0]), f2bf(sb[ii * 8 + 1]),
                                f2bf(sb[ii * 8 + 2]), f2bf(sb[ii * 8 + 3]));
    *(ushort4*)(d + 4) = make_ushort4(f2bf(sb[ii * 8 + 4]), f2bf(sb[ii * 8 + 5]),
                                      f2bf(sb[ii * 8 + 6]), f2bf(sb[ii * 8 + 7]));
  }
  __syncthreads();

  const int t0 = wid * 16;
  floatx4 acc[4] = {};
  floatx4 pacc[4] = {};

#pragma unroll
  for (int ks = 0; ks < 2; ks++) {
    const bf16x8 aq = *(const bf16x8*)&Qs[(t0 + row16) * 72 + ks * 32 + quad * 8];
#pragma unroll
    for (int nt = 0; nt < 4; nt++) {
      const bf16x8 bt = *(const bf16x8*)&Ts[(nt * 16 + row16) * 72 + ks * 32 + quad * 8];
      acc[nt] = __builtin_amdgcn_mfma_f32_16x16x32_bf16(aq, bt, acc[nt], 0, 0, 0);
      const bf16x8 bk = *(const bf16x8*)&Ks[(nt * 16 + row16) * 72 + ks * 32 + quad * 8];
      pacc[nt] = __builtin_amdgcn_mfma_f32_16x16x32_bf16(aq, bk, pacc[nt], 0, 0, 0);
    }
  }
#pragma unroll
  for (int nt = 0; nt < 4; nt++)
#pragma unroll
    for (int r = 0; r < 4; r++) {
      const int tt = t0 + quad * 4 + r, ss = nt * 16 + row16;
      Pb[tt * 72 + ss] = f2bf((ss <= tt) ? pacc[nt][r] : 0.f);
    }
  __syncthreads();

#pragma unroll
  for (int ks = 0; ks < 2; ks++) {
    const bf16x8 ap = *(const bf16x8*)&Pb[(t0 + row16) * 72 + ks * 32 + quad * 8];
#pragma unroll
    for (int nt = 0; nt < 4; nt++) {
      const bf16x8 bv = tfrag(VT, nt * 16 + row16, ks * 16 + quad * 4);
      acc[nt] = __builtin_amdgcn_mfma_f32_16x16x32_bf16(ap, bv, acc[nt], 0, 0, 0);
    }
  }

#pragma unroll
  for (int nt = 0; nt < 4; nt++)
#pragma unroll
    for (int r = 0; r < 4; r++)
      out[gbase + (size_t)(t0 + quad * 4 + r) * DIM + nt * 16 + row16] = acc[nt][r];
}

extern "C" void kernel_launch(void* const* d_in, const int* in_sizes, int n_in,
                              void* d_out, int out_size, void* d_ws, size_t ws_size,
                              hipStream_t stream) {
  const float* query = (const float*)d_in[0];
  const float* key   = (const float*)d_in[1];
  const float* Wq    = (const float*)d_in[2];
  const float* Wk    = (const float*)d_in[3];
  const float* Wv    = (const float*)d_in[4];
  float* out = (float*)d_out;

  // d_ws: [qp 8MB bf16][kp 8MB][vp 8MB][ct 16MB f32] = 40MB
  // xbf (16MB) overlays ct (ct written only after gemm consumed xbf);
  // wbf (6MB) overlays d_out (dead until attn4).
  const size_t PM = (size_t)4 << 20;                 // 4M elements
  ushort_t* qp = (ushort_t*)d_ws;
  ushort_t* kp = qp + PM;
  ushort_t* vp = kp + PM;
  float*    ct = (float*)(vp + PM);
  ushort_t* xbf = (ushort_t*)ct;
  ushort_t* wbf = (ushort_t*)out;

  cast_all<<<dim3(512, 5), 256, 0, stream>>>(query, key, Wq, Wk, Wv, xbf, wbf);

  gemm_fused<<<dim3(192), 512, 0, stream>>>(xbf, wbf, qp, kp, vp);

  chunk_T<<<dim3(NC, H, NB), 256, 0, stream>>>(kp, vp, ct);

  attn4<<<dim3(NC, H, NB), 256, 0, stream>>>(qp, kp, vp, ct, out);
}

// Round 14
// 155.611 us; speedup vs baseline: 1.1434x; 1.1434x over previous
//
#include <hip/hip_runtime.h>

// Causal linear attention (chunked scan), bf16 MFMA end-to-end.
// q = softmax(x Wq^T), k = softmax(x Wk^T), v = x Wv^T   (one fused MFMA GEMM)
// seg_T : per (n,h,seg) walk 4 chunks; T_c = sum_t v_t^T (x) k_t (MFMA);
//         write within-seg EXCLUSIVE prefix P_c (fp32) + segment total.
// attn2 : SegBase = sum_{s'<s} segtot (fp32, LDS); Ts = bf16(SegBase + P_c);
//         out = Q @ Ts^T + tril(Q K^T) @ V   (MFMA, 2 chunks per block-half)
// R14 = R9 verbatim (best measured: 156.7us; gemm 46.2-46.6 in-run).
// Session converged: gemm is structure-bound ~46.5us (550 TF, 1 block/CU at
// 128KB LDS); total-gemm ~110us invariant across 5 tail structures (fixed
// overhead + tail floor); remaining levers < cross-container noise (~0.63x
// board-class variance demonstrated R10/R11/R13 vs R12 on equivalent shapes).

constexpr int DIM  = 1024;
constexpr int H    = 16;
constexpr int DH   = 64;
constexpr int LSEQ = 2048;
constexpr int NB   = 2;
constexpr int MTOK = NB * LSEQ;   // 4096 tokens
constexpr int CS   = 64;          // chunk size
constexpr int NC   = LSEQ / CS;   // 32 chunks
constexpr int SEG  = 8;           // segments per sequence
constexpr int CPS  = NC / SEG;    // 4 chunks per segment

typedef __bf16 bf16x8 __attribute__((ext_vector_type(8)));
typedef float floatx4 __attribute__((ext_vector_type(4)));
typedef unsigned short ushort_t;

__device__ __forceinline__ ushort_t f2bf(float f) {
  unsigned int u = __float_as_uint(f);
  u += 0x7FFFu + ((u >> 16) & 1u);   // RTNE
  return (ushort_t)(u >> 16);
}

__device__ __forceinline__ void async16(void* lds, const void* g) {
  __builtin_amdgcn_global_load_lds(
      (const __attribute__((address_space(1))) unsigned int*)g,
      (__attribute__((address_space(3))) unsigned int*)lds, 16, 0, 0);
}

// read a bf16x8 fragment from a transposed stride-33-uint LDS array
__device__ __forceinline__ bf16x8 tfrag(const unsigned int* T, int row, int uoff) {
  union { bf16x8 v; unsigned int u[4]; } r;
  const unsigned int* p = T + row * 33 + uoff;
  r.u[0] = p[0]; r.u[1] = p[1]; r.u[2] = p[2]; r.u[3] = p[3];
  return r.v;
}

// transpose a 64x64 bf16 tile (global, row stride DIM) into stride-33-uint LDS
// (tid must be 0..255)
__device__ __forceinline__ void transpose_tile(const ushort_t* g, unsigned int* TT, int tid) {
  const int ic = tid & 7, tp = tid >> 3;       // tp 0..31, ic 0..7
  const ushort_t* r0 = g + (size_t)(2 * tp) * DIM + ic * 8;
  union { uint4 q; ushort_t u[8]; } a0, a1;
  a0.q = *(const uint4*)r0;
  a1.q = *(const uint4*)(r0 + DIM);
#pragma unroll
  for (int j = 0; j < 8; j++)
    TT[(8 * ic + j) * 33 + tp] = (unsigned int)a0.u[j] | ((unsigned int)a1.u[j] << 16);
}

// ------------- cast fp32 -> bf16 for query/key and the three weights --------
__global__ __launch_bounds__(256) void cast_all(const float* __restrict__ q,
                                                const float* __restrict__ k,
                                                const float* __restrict__ wq,
                                                const float* __restrict__ wk,
                                                const float* __restrict__ wv,
                                                ushort_t* __restrict__ xbf,
                                                ushort_t* __restrict__ wbf) {
  const int seg = blockIdx.y;
  const float* src;
  ushort_t* dst;
  int n4;
  if (seg == 0)      { src = q;  dst = xbf;                  n4 = (4 << 20) / 4; }
  else if (seg == 1) { src = k;  dst = xbf + (4 << 20);      n4 = (4 << 20) / 4; }
  else if (seg == 2) { src = wq; dst = wbf;                  n4 = (1 << 20) / 4; }
  else if (seg == 3) { src = wk; dst = wbf + (1 << 20);      n4 = (1 << 20) / 4; }
  else               { src = wv; dst = wbf + (2 << 20);      n4 = (1 << 20) / 4; }
  for (int i = blockIdx.x * 256 + threadIdx.x; i < n4; i += gridDim.x * 256) {
    const float4 f = ((const float4*)src)[i];
    ((ushort4*)dst)[i] = make_ushort4(f2bf(f.x), f2bf(f.y), f2bf(f.z), f2bf(f.w));
  }
}

// ----- fused bf16 MFMA GEMM NT: z in {0:q,1:k,2:v}, tile 256x256, BK=64 -----
// R6 schedule (best measured, 46.5us): 8 waves (2M x 4N), 16 K-tiles of BK=64,
// 4 phases/K-tile, counted vmcnt(4) once per K-tile, setprio around MFMA,
// LDS XOR-swizzle chunk^=(row&7) source+read (0 bank conflicts measured).
__global__ __launch_bounds__(512, 2) void gemm_fused(const ushort_t* __restrict__ xbf,
                                                     const ushort_t* __restrict__ wbf,
                                                     ushort_t* __restrict__ qp,
                                                     ushort_t* __restrict__ kp,
                                                     ushort_t* __restrict__ vp) {
  __shared__ __align__(16) ushort_t sh[65536];   // 128 KB
  const int tid = threadIdx.x;

  // XCD-aware decode: 192 blocks = 8 XCDs x 24 (HW round-robins blockIdx%8).
  const int xcd   = blockIdx.x & 7;
  const int local = blockIdx.x >> 3;            // 0..23
  const int T     = xcd * 24 + local;           // 0..191
  const int z     = T >> 6;                     // 0..2
  const int rem   = T & 63;
  const int bm    = (rem >> 2) * 256;
  const int bn    = (rem & 3) * 256;

  const ushort_t* A = xbf + (z ? (size_t)(4 << 20) : 0);
  const ushort_t* W = wbf + (size_t)z * (1 << 20);
  ushort_t* C = (z == 0) ? qp : ((z == 1) ? kp : vp);

  const int lane  = tid & 63;
  const int wid   = tid >> 6;
  const int wr    = wid >> 2, wc = wid & 3;     // wave grid 2(M) x 4(N)
  const int row16 = lane & 15, quad = lane >> 4;

  floatx4 acc[8][4] = {};

  const int srow = tid >> 3;                        // 0..63
  const int lc   = (tid & 7) ^ (srow & 7);
  const ushort_t* pA[2][2];
  const ushort_t* pB[2][2];
#pragma unroll
  for (int h = 0; h < 2; h++)
#pragma unroll
    for (int rnd = 0; rnd < 2; rnd++) {
      pA[h][rnd] = A + (size_t)(bm + h * 128 + rnd * 64 + srow) * DIM + lc * 8;
      pB[h][rnd] = W + (size_t)(bn + h * 128 + rnd * 64 + srow) * DIM + lc * 8;
    }
  char* shW = (char*)sh;

#define STG(b, ism, h, kt)                                          \
  {                                                                 \
    char* d_ = shW + (b) * 65536 + (ism) * 32768 + (h) * 16384 + tid * 16; \
    async16(d_,        ((ism) ? pB : pA)[h][0] + (size_t)(kt) * 64);       \
    async16(d_ + 8192, ((ism) ? pB : pA)[h][1] + (size_t)(kt) * 64);       \
  }

  const int key = row16 & 7;
  const int xc0 = (quad ^ key) * 16;          // kk=0 chunk byte
  const int xc1 = ((4 + quad) ^ key) * 16;    // kk=1 chunk byte
  const int aOff = wr * 16384 + row16 * 128;  // + p*65536 + mt*2048
  const int bOff = 32768 + (wc >> 1) * 16384 + (wc & 1) * 8192 + row16 * 128;
  const char* shR = (const char*)sh;

  bf16x8 aF[4][2], bF[4][2];

#define RD_A4(p, base)                                                        \
  {                                                                           \
    _Pragma("unroll")                                                         \
    for (int mt = 0; mt < 4; mt++) {                                          \
      aF[mt][0] = *(const bf16x8*)(shR + (p) * 65536 + aOff + ((base) + mt) * 2048 + xc0); \
      aF[mt][1] = *(const bf16x8*)(shR + (p) * 65536 + aOff + ((base) + mt) * 2048 + xc1); \
    }                                                                         \
  }
#define RD_B2(p, base)                                                        \
  {                                                                           \
    _Pragma("unroll")                                                         \
    for (int j = 0; j < 2; j++) {                                             \
      bF[(base) + j][0] = *(const bf16x8*)(shR + (p) * 65536 + bOff + ((base) + j) * 2048 + xc0); \
      bF[(base) + j][1] = *(const bf16x8*)(shR + (p) * 65536 + bOff + ((base) + j) * 2048 + xc1); \
    }                                                                         \
  }
#define MFMA8(mb, nb)                                                         \
  {                                                                           \
    _Pragma("unroll")                                                         \
    for (int mt = 0; mt < 4; mt++)                                            \
      _Pragma("unroll")                                                       \
      for (int nt = 0; nt < 2; nt++) {                                        \
        acc[(mb) + mt][(nb) + nt] = __builtin_amdgcn_mfma_f32_16x16x32_bf16(  \
            aF[mt][0], bF[(nb) + nt][0], acc[(mb) + mt][(nb) + nt], 0, 0, 0); \
        acc[(mb) + mt][(nb) + nt] = __builtin_amdgcn_mfma_f32_16x16x32_bf16(  \
            aF[mt][1], bF[(nb) + nt][1], acc[(mb) + mt][(nb) + nt], 0, 0, 0); \
      }                                                                       \
  }
#define BARD()  asm volatile("s_barrier" ::: "memory")
#define LGKM0() asm volatile("s_waitcnt lgkmcnt(0)" ::: "memory")

  STG(0, 0, 0, 0); STG(0, 1, 0, 0);   // 0.A0, 0.B0
  STG(0, 1, 1, 0); STG(0, 0, 1, 0);   // 0.B1, 0.A1
  STG(1, 0, 0, 1); STG(1, 1, 0, 1);   // 1.A0, 1.B0
  asm volatile("s_waitcnt vmcnt(4)" ::: "memory");
  BARD();

  for (int u = 0; u < 16; ++u) {
    const int p  = u & 1;
    const int qb = p ^ 1;
    RD_A4(p, 0); RD_B2(p, 0);
    if (u + 1 < 16) { STG(qb, 1, 1, u + 1); STG(qb, 0, 1, u + 1); }
    BARD(); LGKM0();
    __builtin_amdgcn_s_setprio(1); MFMA8(0, 0); __builtin_amdgcn_s_setprio(0);
    BARD();
    RD_B2(p, 2);
    BARD(); LGKM0();
    __builtin_amdgcn_s_setprio(1); MFMA8(0, 2); __builtin_amdgcn_s_setprio(0);
    BARD();
    RD_A4(p, 4);
    BARD(); LGKM0();
    __builtin_amdgcn_s_setprio(1); MFMA8(4, 0); __builtin_amdgcn_s_setprio(0);
    BARD();
    if (u + 2 < 16) {
      STG(p, 0, 0, u + 2); STG(p, 1, 0, u + 2);
      asm volatile("s_waitcnt vmcnt(4)" ::: "memory");
    } else {
      asm volatile("s_waitcnt vmcnt(0)" ::: "memory");
    }
    BARD();
    __builtin_amdgcn_s_setprio(1); MFMA8(4, 2); __builtin_amdgcn_s_setprio(0);
    BARD();
  }
#undef STG
#undef RD_A4
#undef RD_B2
#undef MFMA8
#undef BARD
#undef LGKM0
  __syncthreads();   // all LDS traffic done before reuse as repack buffer

  if (z < 2) {
    // in-register per-head softmax: row (mt,quad,r) spans nt regs x 16 lanes
#pragma unroll
    for (int mt = 0; mt < 8; mt++)
#pragma unroll
      for (int r = 0; r < 4; r++) {
        float m = fmaxf(fmaxf(acc[mt][0][r], acc[mt][1][r]),
                        fmaxf(acc[mt][2][r], acc[mt][3][r]));
#pragma unroll
        for (int o = 1; o < 16; o <<= 1) m = fmaxf(m, __shfl_xor(m, o, 64));
        float e[4], s = 0.f;
#pragma unroll
        for (int nt = 0; nt < 4; nt++) { e[nt] = __expf(acc[mt][nt][r] - m); s += e[nt]; }
#pragma unroll
        for (int o = 1; o < 16; o <<= 1) s += __shfl_xor(s, o, 64);
        const float inv = 1.f / s;
#pragma unroll
        for (int nt = 0; nt < 4; nt++) acc[mt][nt][r] = e[nt] * inv;
      }
  }

  // epilogue: 4 rounds of 64 rows; repack via LDS (stride 264), 16B stores
  ushort_t* CsB = sh;
#pragma unroll
  for (int p4 = 0; p4 < 4; ++p4) {
    __syncthreads();
    if (wr == (p4 >> 1)) {
      const int mh = (p4 & 1) * 4;
#pragma unroll
      for (int m4 = 0; m4 < 4; m4++)
#pragma unroll
        for (int nt = 0; nt < 4; nt++)
#pragma unroll
          for (int r = 0; r < 4; r++)
            CsB[(m4 * 16 + quad * 4 + r) * 264 + wc * 64 + nt * 16 + row16] =
                f2bf(acc[mh + m4][nt][r]);
    }
    __syncthreads();
#pragma unroll
    for (int it = 0; it < 4; it++) {
      const int ch = tid + it * 512;        // 0..2047 = 64 rows x 32 chunks
      const int row = ch >> 5, ic = ch & 31;
      *(uint4*)&C[(size_t)(bm + p4 * 64 + row) * DIM + bn + ic * 8] =
          *(const uint4*)&CsB[row * 264 + ic * 8];
    }
  }
}

// ---- seg_T: per (n,h,seg) walk CPS chunks; write P_c (excl prefix) + total -
// grid (SEG, H, NB) = 256 blocks (1/CU), 256 threads.
__global__ __launch_bounds__(256) void seg_T(const ushort_t* __restrict__ kp,
                                             const ushort_t* __restrict__ vp,
                                             float* __restrict__ cs,
                                             float* __restrict__ segtot) {
  __shared__ unsigned int KT[64 * 33];
  __shared__ unsigned int VT[64 * 33];
  const int s = blockIdx.x, h = blockIdx.y, n = blockIdx.z;
  const int tid = threadIdx.x;
  const int lane = tid & 63, wid = tid >> 6;
  const int row16 = lane & 15, quad = lane >> 4;
  const int nh = n * H + h;

  floatx4 run[4] = {};
  for (int j = 0; j < CPS; j++) {
    const int c = s * CPS + j;
    const size_t gbase = ((size_t)(n * LSEQ + c * CS)) * DIM + h * DH;
    if (j) __syncthreads();                 // prior chunk's LDS readers done
    transpose_tile(kp + gbase, KT, tid);
    transpose_tile(vp + gbase, VT, tid);
    __syncthreads();

    floatx4 tacc[4] = {};
#pragma unroll
    for (int ks = 0; ks < 2; ks++) {
      const bf16x8 a = tfrag(VT, wid * 16 + row16, ks * 16 + quad * 4);
#pragma unroll
      for (int nt = 0; nt < 4; nt++) {
        const bf16x8 b = tfrag(KT, nt * 16 + row16, ks * 16 + quad * 4);
        tacc[nt] = __builtin_amdgcn_mfma_f32_16x16x32_bf16(a, b, tacc[nt], 0, 0, 0);
      }
    }
    // exclusive within-segment prefix: write BEFORE accumulating
    float* outp = cs + ((size_t)(nh * NC + c)) * (DH * DH);
#pragma unroll
    for (int nt = 0; nt < 4; nt++)
#pragma unroll
      for (int r = 0; r < 4; r++)
        outp[(wid * 16 + quad * 4 + r) * DH + nt * 16 + row16] = run[nt][r];
#pragma unroll
    for (int nt = 0; nt < 4; nt++) run[nt] += tacc[nt];
  }
  float* st = segtot + ((size_t)(nh * SEG + s)) * (DH * DH);
#pragma unroll
  for (int nt = 0; nt < 4; nt++)
#pragma unroll
    for (int r = 0; r < 4; r++)
      st[(wid * 16 + quad * 4 + r) * DH + nt * 16 + row16] = run[nt][r];
}

// ---- attn2: SegBase + P_c -> Ts (bf16); out = Q Ts^T + tril(Q K^T) V -------
// grid (SEG, H, NB) = 256 blocks, 512 threads = 2 halves x 4 waves;
// half processes chunk c = s*CPS + r2*2 + half (2 rounds).
__global__ __launch_bounds__(512) void attn2(const ushort_t* __restrict__ qp,
                                             const ushort_t* __restrict__ kp,
                                             const ushort_t* __restrict__ vp,
                                             const float* __restrict__ cs,
                                             const float* __restrict__ segtot,
                                             float* __restrict__ out) {
  __shared__ float Sb[DH * DH];               // 16 KB
  __shared__ ushort_t Qs[2][64 * 72];
  __shared__ ushort_t Ks[2][64 * 72];
  __shared__ ushort_t Ts[2][64 * 72];
  __shared__ ushort_t Pb[2][64 * 72];
  __shared__ unsigned int VT2[2][64 * 33];
  const int s = blockIdx.x, h = blockIdx.y, n = blockIdx.z;
  const int tid = threadIdx.x;
  const int half = tid >> 8;                  // 0/1
  const int t8   = tid & 255;                 // tid within half
  const int lane = tid & 63;
  const int wl   = (tid >> 6) & 3;            // wave within half
  const int row16 = lane & 15, quad = lane >> 4;
  const int nh = n * H + h;

  // ---- SegBase = sum_{s'<s} segtot[nh][s'] (fp32, 512 thr x 8 elems) ----
  {
    float a8[8] = {0.f, 0.f, 0.f, 0.f, 0.f, 0.f, 0.f, 0.f};
    const float* base = segtot + (size_t)nh * SEG * (DH * DH) + tid * 8;
    for (int sp = 0; sp < s; sp++) {
      const float4 u0 = *(const float4*)(base + (size_t)sp * (DH * DH));
      const float4 u1 = *(const float4*)(base + (size_t)sp * (DH * DH) + 4);
      a8[0] += u0.x; a8[1] += u0.y; a8[2] += u0.z; a8[3] += u0.w;
      a8[4] += u1.x; a8[5] += u1.y; a8[6] += u1.z; a8[7] += u1.w;
    }
#pragma unroll
    for (int i = 0; i < 8; i++) Sb[tid * 8 + i] = a8[i];
  }
  __syncthreads();

  for (int r2 = 0; r2 < 2; r2++) {
    const int c = s * CPS + r2 * 2 + half;
    const size_t gbase = ((size_t)(n * LSEQ + c * CS)) * DIM + h * DH;
    const float* Pc = cs + ((size_t)(nh * NC + c)) * (DH * DH);
    if (r2) __syncthreads();                  // prior round's readers done

    // stage Q,K (bf16) for this half's chunk
#pragma unroll
    for (int it = 0; it < 2; it++) {
      const int ch = t8 + it * 256;           // 0..511
      const int row = ch >> 3, ic = ch & 7;
      *(uint4*)&Qs[half][row * 72 + ic * 8] =
          *(const uint4*)&qp[gbase + (size_t)row * DIM + ic * 8];
      *(uint4*)&Ks[half][row * 72 + ic * 8] =
          *(const uint4*)&kp[gbase + (size_t)row * DIM + ic * 8];
    }
    transpose_tile(vp + gbase, VT2[half], t8);
    // Ts = bf16(SegBase + P_c): 256 thr x 2 x 8 elems
#pragma unroll
    for (int ii = 0; ii < 2; ii++) {
      const int e = (t8 + ii * 256) * 8;      // 0..4088, step 8
      const int row = e >> 6, col = e & 63;
      const float4 p0 = *(const float4*)(Pc + e);
      const float4 p1 = *(const float4*)(Pc + e + 4);
      ushort_t* d = &Ts[half][row * 72 + col];
      *(ushort4*)d = make_ushort4(f2bf(p0.x + Sb[e]),     f2bf(p0.y + Sb[e + 1]),
                                  f2bf(p0.z + Sb[e + 2]), f2bf(p0.w + Sb[e + 3]));
      *(ushort4*)(d + 4) = make_ushort4(f2bf(p1.x + Sb[e + 4]), f2bf(p1.y + Sb[e + 5]),
                                        f2bf(p1.z + Sb[e + 6]), f2bf(p1.w + Sb[e + 7]));
    }
    __syncthreads();

    const int t0 = wl * 16;
    floatx4 acc[4] = {};
    floatx4 pacc[4] = {};

#pragma unroll
    for (int ks = 0; ks < 2; ks++) {
      const bf16x8 aq = *(const bf16x8*)&Qs[half][(t0 + row16) * 72 + ks * 32 + quad * 8];
#pragma unroll
      for (int nt = 0; nt < 4; nt++) {
        const bf16x8 bt = *(const bf16x8*)&Ts[half][(nt * 16 + row16) * 72 + ks * 32 + quad * 8];
        acc[nt] = __builtin_amdgcn_mfma_f32_16x16x32_bf16(aq, bt, acc[nt], 0, 0, 0);
        const bf16x8 bk = *(const bf16x8*)&Ks[half][(nt * 16 + row16) * 72 + ks * 32 + quad * 8];
        pacc[nt] = __builtin_amdgcn_mfma_f32_16x16x32_bf16(aq, bk, pacc[nt], 0, 0, 0);
      }
    }
#pragma unroll
    for (int nt = 0; nt < 4; nt++)
#pragma unroll
      for (int r = 0; r < 4; r++) {
        const int tt = t0 + quad * 4 + r, ss = nt * 16 + row16;
        Pb[half][tt * 72 + ss] = f2bf((ss <= tt) ? pacc[nt][r] : 0.f);
      }
    __syncthreads();

#pragma unroll
    for (int ks = 0; ks < 2; ks++) {
      const bf16x8 ap = *(const bf16x8*)&Pb[half][(t0 + row16) * 72 + ks * 32 + quad * 8];
#pragma unroll
      for (int nt = 0; nt < 4; nt++) {
        const bf16x8 bv = tfrag(VT2[half], nt * 16 + row16, ks * 16 + quad * 4);
        acc[nt] = __builtin_amdgcn_mfma_f32_16x16x32_bf16(ap, bv, acc[nt], 0, 0, 0);
      }
    }

#pragma unroll
    for (int nt = 0; nt < 4; nt++)
#pragma unroll
      for (int r = 0; r < 4; r++)
        out[gbase + (size_t)(t0 + quad * 4 + r) * DIM + nt * 16 + row16] = acc[nt][r];
  }
}

extern "C" void kernel_launch(void* const* d_in, const int* in_sizes, int n_in,
                              void* d_out, int out_size, void* d_ws, size_t ws_size,
                              hipStream_t stream) {
  const float* query = (const float*)d_in[0];
  const float* key   = (const float*)d_in[1];
  const float* Wq    = (const float*)d_in[2];
  const float* Wk    = (const float*)d_in[3];
  const float* Wv    = (const float*)d_in[4];
  float* out = (float*)d_out;

  // d_ws: [qp 8MB bf16][kp 8MB][vp 8MB][cs 16MB f32][segtot 4MB f32] = 44MB
  // xbf (16MB) overlays cs; wbf (6MB) overlays d_out (dead until attn2)
  const size_t PM = (size_t)4 << 20;                 // 4M elements
  ushort_t* qp = (ushort_t*)d_ws;
  ushort_t* kp = qp + PM;
  ushort_t* vp = kp + PM;
  float*    cs = (float*)(vp + PM);
  float*    segtot = cs + PM;
  ushort_t* xbf = (ushort_t*)cs;
  ushort_t* wbf = (ushort_t*)out;

  cast_all<<<dim3(512, 5), 256, 0, stream>>>(query, key, Wq, Wk, Wv, xbf, wbf);

  gemm_fused<<<dim3(192), 512, 0, stream>>>(xbf, wbf, qp, kp, vp);

  seg_T<<<dim3(SEG, H, NB), 256, 0, stream>>>(kp, vp, cs, segtot);

  attn2<<<dim3(SEG, H, NB), 512, 0, stream>>>(qp, kp, vp, cs, segtot, out);
}